// Round 9
// baseline (486.915 us; speedup 1.0000x reference)
//
#include <hip/hip_runtime.h>
#include <hip/hip_bf16.h>
#include <math.h>

#define N_TOK 4096
#define DIM   1024
#define NEXP  8
#define IDIM  2048
#define TWOI  4096
#define CAP   1280

#define W1_BLOCKS (64 * 16 * NEXP)   // 8192 transpose tiles for W1
#define W2_BLOCKS (16 * 32 * NEXP)   // 4096 transpose tiles for W2
#define ROUTER_BLOCKS (N_TOK / 4)    // 1024

// gemm1 grid: x=32 n-tiles, y=10 m-tiles, z = 8 experts + 13 trans planes (320 blocks each)
#define G1X 32
#define G1Y 10
#define G1_TRANS_Z ((W2_BLOCKS + G1X * G1Y - 1) / (G1X * G1Y))  // 13

using short8  = __attribute__((ext_vector_type(8))) short;
using floatx4 = __attribute__((ext_vector_type(4))) float;

__device__ __forceinline__ unsigned short f2b(float f) {
  __hip_bfloat16 h = __float2bfloat16(f);
  return *reinterpret_cast<unsigned short*>(&h);
}

// async global->LDS, 16B per lane. LDS dst = wave-uniform base + lane*16.
__device__ __forceinline__ void async16(const unsigned short* g, unsigned short* l) {
  __builtin_amdgcn_global_load_lds(
      (const __attribute__((address_space(1))) unsigned int*)g,
      (__attribute__((address_space(3))) unsigned int*)l,
      16, 0, 0);
}

// ---------------- prologue: W1 transpose+convert AND router (+ zero out) ----------------
__global__ __launch_bounds__(256) void prologue_kernel(const float* __restrict__ W1,
                                                       unsigned short* __restrict__ w1t,
                                                       const float* __restrict__ x,
                                                       const float* __restrict__ Wg,
                                                       unsigned short* __restrict__ xb,
                                                       int* __restrict__ top_i,
                                                       float* __restrict__ gates,
                                                       float* __restrict__ out) {
  __shared__ __align__(16) float smem_f[NEXP * DIM];   // 32 KB, overlaid
  int bid = blockIdx.x;
  int tid = threadIdx.x;

  if (bid < W1_BLOCKS) {
    float (*tile)[65] = reinterpret_cast<float (*)[65]>(smem_f);
    int e = bid >> 10;
    int t = bid & 1023;
    const int R = DIM, C = TWOI;
    int r0 = (t & 15) * 64;
    int c0 = (t >> 4) * 64;
    const float* s = W1 + (size_t)e * R * C;
    unsigned short* d = w1t + (size_t)e * R * C;
    int tr = tid >> 4, tc = (tid & 15) * 4;
#pragma unroll
    for (int i = 0; i < 4; i++) {
      float4 v = *reinterpret_cast<const float4*>(&s[(size_t)(r0 + tr + i * 16) * C + c0 + tc]);
      tile[tr + i * 16][tc]     = v.x;
      tile[tr + i * 16][tc + 1] = v.y;
      tile[tr + i * 16][tc + 2] = v.z;
      tile[tr + i * 16][tc + 3] = v.w;
    }
    __syncthreads();
#pragma unroll
    for (int j = 0; j < 4; j++) {
      int c = (tid >> 4) + j * 16;
      int r4 = (tid & 15) * 4;
      ushort4 o;
      o.x = f2b(tile[r4][c]);
      o.y = f2b(tile[r4 + 1][c]);
      o.z = f2b(tile[r4 + 2][c]);
      o.w = f2b(tile[r4 + 3][c]);
      *reinterpret_cast<ushort4*>(&d[(size_t)(c0 + c) * R + r0 + r4]) = o;
    }
  } else {
    int rb = bid - W1_BLOCKS;
    // zero the output rows for this block's 4 tokens (gemm2 accumulates atomically)
    {
      float4 z4 = {0.f, 0.f, 0.f, 0.f};
      float4* ob = reinterpret_cast<float4*>(out + (size_t)rb * 4 * DIM);
#pragma unroll
      for (int i = 0; i < 4; i++) ob[tid + i * 256] = z4;
    }
    float* wg = smem_f;
    for (int i = tid * 4; i < NEXP * DIM; i += 256 * 4) {
      *reinterpret_cast<float4*>(wg + i) = *reinterpret_cast<const float4*>(Wg + i);
    }
    __syncthreads();
    int wave = tid >> 6, lane = tid & 63;
    int t = rb * 4 + wave;
    const float* xr = x + (size_t)t * DIM;
    unsigned short* xbr = xb + (size_t)t * DIM;
    double acc[NEXP];
#pragma unroll
    for (int e = 0; e < NEXP; e++) acc[e] = 0.0;
    for (int i = lane; i < DIM; i += 64) {
      float xf = xr[i];
      xbr[i] = f2b(xf);
      double xv = (double)xf;
#pragma unroll
      for (int e = 0; e < NEXP; e++) acc[e] += xv * (double)wg[e * DIM + i];
    }
#pragma unroll
    for (int e = 0; e < NEXP; e++) {
#pragma unroll
      for (int m = 1; m < 64; m <<= 1) acc[e] += __shfl_xor(acc[e], m, 64);
    }
    if (lane == 0) {
      int i0 = 0; double v0 = acc[0];
      for (int e = 1; e < NEXP; e++) { if (acc[e] > v0) { v0 = acc[e]; i0 = e; } }
      int i1 = -1; double v1 = -1e300;
      for (int e = 0; e < NEXP; e++) { if (e != i0 && acc[e] > v1) { v1 = acc[e]; i1 = e; } }
      double e1 = exp(v1 - v0);
      float g0 = (float)(1.0 / (1.0 + e1));
      float g1 = (float)(e1 / (1.0 + e1));
      top_i[t * 2] = i0; top_i[t * 2 + 1] = i1;
      gates[t * 2] = g0; gates[t * 2 + 1] = g1;
    }
  }
}

// ---------------- capacity scan (deterministic, token-major slot order) ----------------
__global__ __launch_bounds__(1024) void scan_kernel(const int* __restrict__ top_i,
                                                    const float* __restrict__ gates,
                                                    int* __restrict__ rowtok,
                                                    float* __restrict__ rowgate,
                                                    int* __restrict__ cnt) {
  __shared__ int hist[NEXP][1024];
  int t = threadIdx.x;
  int s0 = t * 8;
  int eloc[8];
  int c[NEXP];
#pragma unroll
  for (int e = 0; e < NEXP; e++) c[e] = 0;
#pragma unroll
  for (int j = 0; j < 8; j++) { int e = top_i[s0 + j]; eloc[j] = e; c[e]++; }
#pragma unroll
  for (int e = 0; e < NEXP; e++) hist[e][t] = c[e];
  __syncthreads();
  for (int step = 1; step < 1024; step <<= 1) {
    int tmp[NEXP];
#pragma unroll
    for (int e = 0; e < NEXP; e++) tmp[e] = (t >= step) ? hist[e][t - step] : 0;
    __syncthreads();
#pragma unroll
    for (int e = 0; e < NEXP; e++) hist[e][t] += tmp[e];
    __syncthreads();
  }
  int base[NEXP];
#pragma unroll
  for (int e = 0; e < NEXP; e++) base[e] = hist[e][t] - c[e];
  if (t < NEXP) {
    int tot = hist[t][1023];
    cnt[t] = tot < CAP ? tot : CAP;
  }
#pragma unroll
  for (int j = 0; j < 8; j++) {
    int s = s0 + j;
    int e = eloc[j];
    int pos = base[e]++;
    if (pos < CAP) {
      rowtok[e * CAP + pos]  = s >> 1;   // token id (dropped slots never recorded)
      rowgate[e * CAP + pos] = gates[s];
    }
  }
}

// ---------------- GEMM1 + GLU (z<8)  |  W2 transpose (z>=8) ----------------
// 32 KB single-stage structure, natural dispatch order (5 blocks/CU; cross-block TLP
// covers the syncthreads drain — m114/m97 mechanism; XCD swizzle refuted in R6: 2x FETCH).
__global__ __launch_bounds__(256, 5) void gemm1_kernel(const unsigned short* __restrict__ xb,
                                                       const unsigned short* __restrict__ w1t,
                                                       const int* __restrict__ rowtok,
                                                       const int* __restrict__ cnt,
                                                       unsigned short* __restrict__ H,
                                                       const float* __restrict__ W2,
                                                       unsigned short* __restrict__ w2t) {
  __shared__ __align__(16) unsigned char smem[32768];  // gemm: 32 KB; trans overlay: 16.6 KB
  int tid  = threadIdx.x;
  int z = blockIdx.z;

  if (z >= NEXP) {
    // ---- W2 transpose plane ----
    int id = (z - NEXP) * (G1X * G1Y) + blockIdx.y * G1X + blockIdx.x;
    if (id >= W2_BLOCKS) return;
    float (*tile)[65] = reinterpret_cast<float (*)[65]>(smem);
    int e = id >> 9;
    int t = id & 511;
    const int R = IDIM, C = DIM;
    int r0 = (t & 31) * 64;
    int c0 = (t >> 5) * 64;
    const float* s = W2 + (size_t)e * R * C;
    unsigned short* d = w2t + (size_t)e * R * C;
    int tr = tid >> 4, tc = (tid & 15) * 4;
#pragma unroll
    for (int i = 0; i < 4; i++) {
      float4 v = *reinterpret_cast<const float4*>(&s[(size_t)(r0 + tr + i * 16) * C + c0 + tc]);
      tile[tr + i * 16][tc]     = v.x;
      tile[tr + i * 16][tc + 1] = v.y;
      tile[tr + i * 16][tc + 2] = v.z;
      tile[tr + i * 16][tc + 3] = v.w;
    }
    __syncthreads();
#pragma unroll
    for (int j = 0; j < 4; j++) {
      int c = (tid >> 4) + j * 16;
      int r4 = (tid & 15) * 4;
      ushort4 o;
      o.x = f2b(tile[r4][c]);
      o.y = f2b(tile[r4 + 1][c]);
      o.z = f2b(tile[r4 + 2][c]);
      o.w = f2b(tile[r4 + 3][c]);
      *reinterpret_cast<ushort4*>(&d[(size_t)(c0 + c) * R + r0 + r4]) = o;
    }
    return;
  }

  // ---- gemm1 path (natural order: consecutive blocks share the A-panel) ----
  int e  = z;
  int m0 = blockIdx.y * 128;
  int i0 = blockIdx.x * 64;
  int cnte = cnt[e];
  if (m0 >= cnte) return;

  unsigned short* As[2] = { (unsigned short*)smem,           (unsigned short*)(smem + 8192) };
  unsigned short* Bi[2] = { (unsigned short*)(smem + 16384), (unsigned short*)(smem + 20480) };
  unsigned short* Bg[2] = { (unsigned short*)(smem + 24576), (unsigned short*)(smem + 28672) };

  int lane = tid & 63;
  int wave = tid >> 6;

  int srA0 = wave * 32 + (lane >> 2);
  int srA1 = srA0 + 16;
  int srB  = wave * 16 + (lane >> 2);
  int sk   = (lane & 3) * 8;

  int ma0 = m0 + srA0, ma1 = m0 + srA1;
  int tok0 = (ma0 < cnte) ? rowtok[e * CAP + ma0] : 0;
  int tok1 = (ma1 < cnte) ? rowtok[e * CAP + ma1] : 0;

  const unsigned short* w1e = w1t + (size_t)e * TWOI * DIM;
  const unsigned short* gA0 = xb + (size_t)tok0 * DIM + sk;
  const unsigned short* gA1 = xb + (size_t)tok1 * DIM + sk;
  const unsigned short* gBi = w1e + (size_t)(i0 + srB) * DIM + sk;
  const unsigned short* gBg = w1e + (size_t)(i0 + srB + IDIM) * DIM + sk;

  int lane16 = lane & 15;
  int quad   = lane >> 4;
  int wm = (wave & 1) * 64;
  int wn = (wave >> 1) * 32;

  floatx4 acc_i[4][2], acc_g[4][2];
#pragma unroll
  for (int i = 0; i < 4; i++)
#pragma unroll
    for (int j = 0; j < 2; j++) {
      acc_i[i][j] = (floatx4){0.f, 0.f, 0.f, 0.f};
      acc_g[i][j] = (floatx4){0.f, 0.f, 0.f, 0.f};
    }

  for (int k0 = 0; k0 < DIM; k0 += 64) {
    __syncthreads();
#pragma unroll
    for (int b = 0; b < 2; b++) {
      int kk = k0 + b * 32;
      async16(gA0 + kk, As[b] + (wave * 2 + 0) * 512);
      async16(gA1 + kk, As[b] + (wave * 2 + 1) * 512);
      async16(gBi + kk, Bi[b] + wave * 512);
      async16(gBg + kk, Bg[b] + wave * 512);
    }
    __syncthreads();

#pragma unroll
    for (int b = 0; b < 2; b++) {
      short8 a[4];
#pragma unroll
      for (int i = 0; i < 4; i++)
        a[i] = *(const short8*)&As[b][(wm + i * 16 + lane16) * 32 + quad * 8];
#pragma unroll
      for (int j = 0; j < 2; j++) {
        short8 bi = *(const short8*)&Bi[b][(wn + j * 16 + lane16) * 32 + quad * 8];
#pragma unroll
        for (int i = 0; i < 4; i++)
          acc_i[i][j] = __builtin_amdgcn_mfma_f32_16x16x32_bf16(a[i], bi, acc_i[i][j], 0, 0, 0);
        short8 bg = *(const short8*)&Bg[b][(wn + j * 16 + lane16) * 32 + quad * 8];
#pragma unroll
        for (int i = 0; i < 4; i++)
          acc_g[i][j] = __builtin_amdgcn_mfma_f32_16x16x32_bf16(a[i], bg, acc_g[i][j], 0, 0, 0);
      }
    }
  }

  unsigned short* He = H + (size_t)e * CAP * IDIM;
#pragma unroll
  for (int i = 0; i < 4; i++) {
#pragma unroll
    for (int r = 0; r < 4; r++) {
      int m = m0 + wm + i * 16 + quad * 4 + r;
#pragma unroll
      for (int j = 0; j < 2; j++) {
        int n = i0 + wn + j * 16 + lane16;
        float vi = acc_i[i][j][r];
        float vg = acc_g[i][j][r];
        float h = 0.5f * vi * (1.0f + erff(vi * 0.70710678118654752f)) * vg;
        He[(size_t)m * IDIM + n] = f2b(h);
      }
    }
  }
}

// ---------------- GEMM2: 128x64 tiles (1280 blocks = 5/CU; was 640 = 2.5/CU grid-limited),
// same staging/fragment structure as gemm1, gated atomic accumulate into out. ----------------
__global__ __launch_bounds__(256, 6) void gemm2_kernel(const unsigned short* __restrict__ H,
                                                       const unsigned short* __restrict__ w2t,
                                                       const int* __restrict__ cnt,
                                                       const int* __restrict__ rowtok,
                                                       const float* __restrict__ rowgate,
                                                       float* __restrict__ out) {
  int e  = blockIdx.z;
  int m0 = blockIdx.y * 128;
  int n0 = blockIdx.x * 64;
  int cnte = cnt[e];
  if (m0 >= cnte) return;

  __shared__ __align__(16) unsigned char smem[24576];  // A 16 KB + B 8 KB
  unsigned short* As[2] = { (unsigned short*)smem,           (unsigned short*)(smem + 8192) };
  unsigned short* Bs[2] = { (unsigned short*)(smem + 16384), (unsigned short*)(smem + 20480) };

  int tid  = threadIdx.x;
  int lane = tid & 63;
  int wave = tid >> 6;

  int srA0 = wave * 32 + (lane >> 2);
  int srA1 = srA0 + 16;
  int srB  = wave * 16 + (lane >> 2);
  int sk   = (lane & 3) * 8;

  const unsigned short* He  = H + (size_t)e * CAP * IDIM;
  const unsigned short* w2e = w2t + (size_t)e * DIM * IDIM;
  const unsigned short* gA0 = He + (size_t)(m0 + srA0) * IDIM + sk;
  const unsigned short* gA1 = He + (size_t)(m0 + srA1) * IDIM + sk;
  const unsigned short* gB  = w2e + (size_t)(n0 + srB) * IDIM + sk;

  int lane16 = lane & 15;
  int quad   = lane >> 4;
  int wm = (wave & 1) * 64;
  int wn = (wave >> 1) * 32;

  floatx4 acc[4][2];
#pragma unroll
  for (int i = 0; i < 4; i++)
#pragma unroll
    for (int j = 0; j < 2; j++) acc[i][j] = (floatx4){0.f, 0.f, 0.f, 0.f};

  for (int k0 = 0; k0 < IDIM; k0 += 64) {
    __syncthreads();
#pragma unroll
    for (int b = 0; b < 2; b++) {
      int kk = k0 + b * 32;
      async16(gA0 + kk, As[b] + (wave * 2 + 0) * 512);
      async16(gA1 + kk, As[b] + (wave * 2 + 1) * 512);
      async16(gB + kk,  Bs[b] + wave * 512);
    }
    __syncthreads();

#pragma unroll
    for (int b = 0; b < 2; b++) {
      short8 a[4];
#pragma unroll
      for (int i = 0; i < 4; i++)
        a[i] = *(const short8*)&As[b][(wm + i * 16 + lane16) * 32 + quad * 8];
#pragma unroll
      for (int j = 0; j < 2; j++) {
        short8 bb = *(const short8*)&Bs[b][(wn + j * 16 + lane16) * 32 + quad * 8];
#pragma unroll
        for (int i = 0; i < 4; i++)
          acc[i][j] = __builtin_amdgcn_mfma_f32_16x16x32_bf16(a[i], bb, acc[i][j], 0, 0, 0);
      }
    }
  }

#pragma unroll
  for (int i = 0; i < 4; i++) {
#pragma unroll
    for (int r = 0; r < 4; r++) {
      int m = m0 + wm + i * 16 + quad * 4 + r;
      if (m < cnte) {
        int tok = rowtok[e * CAP + m];
        float g = rowgate[e * CAP + m];
        float* orow = out + (size_t)tok * DIM;
#pragma unroll
        for (int j = 0; j < 2; j++) {
          int n = n0 + wn + j * 16 + lane16;
          atomicAdd(&orow[n], g * acc[i][j][r]);
        }
      }
    }
  }
}

// ---------------- launch ----------------
extern "C" void kernel_launch(void* const* d_in, const int* in_sizes, int n_in,
                              void* d_out, int out_size, void* d_ws, size_t ws_size,
                              hipStream_t stream) {
  const float* x  = (const float*)d_in[0];
  const float* Wg = (const float*)d_in[1];
  const float* W1 = (const float*)d_in[2];
  const float* W2 = (const float*)d_in[3];
  float* out = (float*)d_out;

  char* ws = (char*)d_ws;
  size_t off = 0;
  auto alloc = [&](size_t bytes) -> void* {
    void* p = ws + off;
    off = (off + bytes + 255) & ~(size_t)255;
    return p;
  };
  int*   top_i   = (int*)alloc((size_t)N_TOK * 2 * sizeof(int));
  float* gates   = (float*)alloc((size_t)N_TOK * 2 * sizeof(float));
  int*   rowtok  = (int*)alloc((size_t)NEXP * CAP * sizeof(int));
  float* rowgate = (float*)alloc((size_t)NEXP * CAP * sizeof(float));
  int*   cnt     = (int*)alloc((size_t)NEXP * sizeof(int));
  unsigned short* xb  = (unsigned short*)alloc((size_t)N_TOK * DIM * 2);
  unsigned short* w1t = (unsigned short*)alloc((size_t)NEXP * TWOI * DIM * 2);
  unsigned short* w2t = (unsigned short*)alloc((size_t)NEXP * DIM * IDIM * 2);
  unsigned short* Hb  = (unsigned short*)alloc((size_t)NEXP * CAP * IDIM * 2);
  if (off > ws_size) return;

  hipLaunchKernelGGL(prologue_kernel, dim3(W1_BLOCKS + ROUTER_BLOCKS), dim3(256), 0, stream,
                     W1, w1t, x, Wg, xb, top_i, gates, out);
  hipLaunchKernelGGL(scan_kernel, dim3(1), dim3(1024), 0, stream,
                     top_i, gates, rowtok, rowgate, cnt);
  hipLaunchKernelGGL(gemm1_kernel, dim3(G1X, G1Y, NEXP + G1_TRANS_Z), dim3(256), 0, stream,
                     xb, w1t, rowtok, cnt, Hb, W2, w2t);
  hipLaunchKernelGGL(gemm2_kernel, dim3(DIM / 64, CAP / 128, NEXP), dim3(256), 0, stream,
                     Hb, w2t, cnt, rowtok, rowgate, out);
}

// Round 13
// 441.025 us; speedup vs baseline: 1.1041x; 1.1041x over previous
//
#include <hip/hip_runtime.h>
#include <hip/hip_bf16.h>
#include <math.h>

#define N_TOK 4096
#define DIM   1024
#define NEXP  8
#define IDIM  2048
#define TWOI  4096
#define CAP   1280

#define W1_BLOCKS (64 * 16 * NEXP)     // 8192 transpose tiles for W1
#define W1_TBLOCKS (W1_BLOCKS / 2)     // 4096 blocks, 2 tiles each
#define W2_BLOCKS (16 * 32 * NEXP)     // 4096 transpose tiles for W2
#define ROUTER_BLOCKS (N_TOK / 4)      // 1024

// gemm1 grid: x=32 n-tiles, y=10 m-tiles, z = 8 experts + 13 trans planes (320 blocks each)
#define G1X 32
#define G1Y 10
#define G1_TRANS_Z ((W2_BLOCKS + G1X * G1Y - 1) / (G1X * G1Y))  // 13

using short8  = __attribute__((ext_vector_type(8))) short;
using floatx4 = __attribute__((ext_vector_type(4))) float;

__device__ __forceinline__ unsigned short f2b(float f) {
  __hip_bfloat16 h = __float2bfloat16(f);
  return *reinterpret_cast<unsigned short*>(&h);
}

// async global->LDS, 16B per lane. LDS dst = wave-uniform base + lane*16.
__device__ __forceinline__ void async16(const unsigned short* g, unsigned short* l) {
  __builtin_amdgcn_global_load_lds(
      (const __attribute__((address_space(1))) unsigned int*)g,
      (__attribute__((address_space(3))) unsigned int*)l,
      16, 0, 0);
}

// ---------------- prologue: W1 transpose+convert (2 tiles/block) AND router (+ zero out) ----------------
__global__ __launch_bounds__(256) void prologue_kernel(const float* __restrict__ W1,
                                                       unsigned short* __restrict__ w1t,
                                                       const float* __restrict__ x,
                                                       const float* __restrict__ Wg,
                                                       unsigned short* __restrict__ xb,
                                                       int* __restrict__ top_i,
                                                       float* __restrict__ gates,
                                                       float* __restrict__ out) {
  __shared__ __align__(16) float smem_f[NEXP * DIM];   // 32 KB, overlaid
  int bid = blockIdx.x;
  int tid = threadIdx.x;

  if (bid < W1_TBLOCKS) {
    float (*tile)[65] = reinterpret_cast<float (*)[65]>(smem_f);
    int tr = tid >> 4, tc = (tid & 15) * 4;
#pragma unroll
    for (int half = 0; half < 2; ++half) {
      int id = bid * 2 + half;
      int e = id >> 10;
      int t = id & 1023;
      const int R = DIM, C = TWOI;
      int r0 = (t & 15) * 64;
      int c0 = (t >> 4) * 64;
      const float* s = W1 + (size_t)e * R * C;
      unsigned short* d = w1t + (size_t)e * R * C;
#pragma unroll
      for (int i = 0; i < 4; i++) {
        float4 v = *reinterpret_cast<const float4*>(&s[(size_t)(r0 + tr + i * 16) * C + c0 + tc]);
        tile[tr + i * 16][tc]     = v.x;
        tile[tr + i * 16][tc + 1] = v.y;
        tile[tr + i * 16][tc + 2] = v.z;
        tile[tr + i * 16][tc + 3] = v.w;
      }
      __syncthreads();
#pragma unroll
      for (int j = 0; j < 4; j++) {
        int c = (tid >> 4) + j * 16;
        int r4 = (tid & 15) * 4;
        ushort4 o;
        o.x = f2b(tile[r4][c]);
        o.y = f2b(tile[r4 + 1][c]);
        o.z = f2b(tile[r4 + 2][c]);
        o.w = f2b(tile[r4 + 3][c]);
        *reinterpret_cast<ushort4*>(&d[(size_t)(c0 + c) * R + r0 + r4]) = o;
      }
      __syncthreads();   // tile buffer reused by next half
    }
  } else {
    int rb = bid - W1_TBLOCKS;
    // zero the output rows for this block's 4 tokens (gemm2 accumulates atomically)
    {
      float4 z4 = {0.f, 0.f, 0.f, 0.f};
      float4* ob = reinterpret_cast<float4*>(out + (size_t)rb * 4 * DIM);
#pragma unroll
      for (int i = 0; i < 4; i++) ob[tid + i * 256] = z4;
    }
    float* wg = smem_f;
    for (int i = tid * 4; i < NEXP * DIM; i += 256 * 4) {
      *reinterpret_cast<float4*>(wg + i) = *reinterpret_cast<const float4*>(Wg + i);
    }
    __syncthreads();
    int wave = tid >> 6, lane = tid & 63;
    int t = rb * 4 + wave;
    const float* xr = x + (size_t)t * DIM;
    unsigned short* xbr = xb + (size_t)t * DIM;
    double acc[NEXP];
#pragma unroll
    for (int e = 0; e < NEXP; e++) acc[e] = 0.0;
    for (int i = lane; i < DIM; i += 64) {
      float xf = xr[i];
      xbr[i] = f2b(xf);
      double xv = (double)xf;
#pragma unroll
      for (int e = 0; e < NEXP; e++) acc[e] += xv * (double)wg[e * DIM + i];
    }
#pragma unroll
    for (int e = 0; e < NEXP; e++) {
#pragma unroll
      for (int m = 1; m < 64; m <<= 1) acc[e] += __shfl_xor(acc[e], m, 64);
    }
    if (lane == 0) {
      int i0 = 0; double v0 = acc[0];
      for (int e = 1; e < NEXP; e++) { if (acc[e] > v0) { v0 = acc[e]; i0 = e; } }
      int i1 = -1; double v1 = -1e300;
      for (int e = 0; e < NEXP; e++) { if (e != i0 && acc[e] > v1) { v1 = acc[e]; i1 = e; } }
      double e1 = exp(v1 - v0);
      float g0 = (float)(1.0 / (1.0 + e1));
      float g1 = (float)(e1 / (1.0 + e1));
      top_i[t * 2] = i0; top_i[t * 2 + 1] = i1;
      gates[t * 2] = g0; gates[t * 2 + 1] = g1;
    }
  }
}

// ---------------- capacity scan (deterministic, token-major slot order) ----------------
__global__ __launch_bounds__(1024) void scan_kernel(const int* __restrict__ top_i,
                                                    const float* __restrict__ gates,
                                                    int* __restrict__ rowtok,
                                                    float* __restrict__ rowgate,
                                                    int* __restrict__ cnt) {
  __shared__ int hist[NEXP][1024];
  int t = threadIdx.x;
  int s0 = t * 8;
  int eloc[8];
  int c[NEXP];
#pragma unroll
  for (int e = 0; e < NEXP; e++) c[e] = 0;
#pragma unroll
  for (int j = 0; j < 8; j++) { int e = top_i[s0 + j]; eloc[j] = e; c[e]++; }
#pragma unroll
  for (int e = 0; e < NEXP; e++) hist[e][t] = c[e];
  __syncthreads();
  for (int step = 1; step < 1024; step <<= 1) {
    int tmp[NEXP];
#pragma unroll
    for (int e = 0; e < NEXP; e++) tmp[e] = (t >= step) ? hist[e][t - step] : 0;
    __syncthreads();
#pragma unroll
    for (int e = 0; e < NEXP; e++) hist[e][t] += tmp[e];
    __syncthreads();
  }
  int base[NEXP];
#pragma unroll
  for (int e = 0; e < NEXP; e++) base[e] = hist[e][t] - c[e];
  if (t < NEXP) {
    int tot = hist[t][1023];
    cnt[t] = tot < CAP ? tot : CAP;
  }
#pragma unroll
  for (int j = 0; j < 8; j++) {
    int s = s0 + j;
    int e = eloc[j];
    int pos = base[e]++;
    if (pos < CAP) {
      rowtok[e * CAP + pos]  = s >> 1;   // token id (dropped slots never recorded)
      rowgate[e * CAP + pos] = gates[s];
    }
  }
}

// ---------------- GEMM1 + GLU (z<8)  |  W2 transpose (z>=8) ----------------
// 32 KB single-stage structure, natural dispatch order, launch_bounds(256,4)
// (R9: (256,5) squeezed VGPR 60->48 and cost +40 µs with no occupancy gain — reverted).
__global__ __launch_bounds__(256, 4) void gemm1_kernel(const unsigned short* __restrict__ xb,
                                                       const unsigned short* __restrict__ w1t,
                                                       const int* __restrict__ rowtok,
                                                       const int* __restrict__ cnt,
                                                       unsigned short* __restrict__ H,
                                                       const float* __restrict__ W2,
                                                       unsigned short* __restrict__ w2t) {
  __shared__ __align__(16) unsigned char smem[32768];  // gemm: 32 KB; trans overlay: 16.6 KB
  int tid  = threadIdx.x;
  int z = blockIdx.z;

  if (z >= NEXP) {
    // ---- W2 transpose plane ----
    int id = (z - NEXP) * (G1X * G1Y) + blockIdx.y * G1X + blockIdx.x;
    if (id >= W2_BLOCKS) return;
    float (*tile)[65] = reinterpret_cast<float (*)[65]>(smem);
    int e = id >> 9;
    int t = id & 511;
    const int R = IDIM, C = DIM;
    int r0 = (t & 31) * 64;
    int c0 = (t >> 5) * 64;
    const float* s = W2 + (size_t)e * R * C;
    unsigned short* d = w2t + (size_t)e * R * C;
    int tr = tid >> 4, tc = (tid & 15) * 4;
#pragma unroll
    for (int i = 0; i < 4; i++) {
      float4 v = *reinterpret_cast<const float4*>(&s[(size_t)(r0 + tr + i * 16) * C + c0 + tc]);
      tile[tr + i * 16][tc]     = v.x;
      tile[tr + i * 16][tc + 1] = v.y;
      tile[tr + i * 16][tc + 2] = v.z;
      tile[tr + i * 16][tc + 3] = v.w;
    }
    __syncthreads();
#pragma unroll
    for (int j = 0; j < 4; j++) {
      int c = (tid >> 4) + j * 16;
      int r4 = (tid & 15) * 4;
      ushort4 o;
      o.x = f2b(tile[r4][c]);
      o.y = f2b(tile[r4 + 1][c]);
      o.z = f2b(tile[r4 + 2][c]);
      o.w = f2b(tile[r4 + 3][c]);
      *reinterpret_cast<ushort4*>(&d[(size_t)(c0 + c) * R + r0 + r4]) = o;
    }
    return;
  }

  // ---- gemm1 path (natural order: consecutive blocks share the A-panel) ----
  int e  = z;
  int m0 = blockIdx.y * 128;
  int i0 = blockIdx.x * 64;
  int cnte = cnt[e];
  if (m0 >= cnte) return;

  unsigned short* As[2] = { (unsigned short*)smem,           (unsigned short*)(smem + 8192) };
  unsigned short* Bi[2] = { (unsigned short*)(smem + 16384), (unsigned short*)(smem + 20480) };
  unsigned short* Bg[2] = { (unsigned short*)(smem + 24576), (unsigned short*)(smem + 28672) };

  int lane = tid & 63;
  int wave = tid >> 6;

  int srA0 = wave * 32 + (lane >> 2);
  int srA1 = srA0 + 16;
  int srB  = wave * 16 + (lane >> 2);
  int sk   = (lane & 3) * 8;

  int ma0 = m0 + srA0, ma1 = m0 + srA1;
  int tok0 = (ma0 < cnte) ? rowtok[e * CAP + ma0] : 0;
  int tok1 = (ma1 < cnte) ? rowtok[e * CAP + ma1] : 0;

  const unsigned short* w1e = w1t + (size_t)e * TWOI * DIM;
  const unsigned short* gA0 = xb + (size_t)tok0 * DIM + sk;
  const unsigned short* gA1 = xb + (size_t)tok1 * DIM + sk;
  const unsigned short* gBi = w1e + (size_t)(i0 + srB) * DIM + sk;
  const unsigned short* gBg = w1e + (size_t)(i0 + srB + IDIM) * DIM + sk;

  int lane16 = lane & 15;
  int quad   = lane >> 4;
  int wm = (wave & 1) * 64;
  int wn = (wave >> 1) * 32;

  floatx4 acc_i[4][2], acc_g[4][2];
#pragma unroll
  for (int i = 0; i < 4; i++)
#pragma unroll
    for (int j = 0; j < 2; j++) {
      acc_i[i][j] = (floatx4){0.f, 0.f, 0.f, 0.f};
      acc_g[i][j] = (floatx4){0.f, 0.f, 0.f, 0.f};
    }

  for (int k0 = 0; k0 < DIM; k0 += 64) {
    __syncthreads();
#pragma unroll
    for (int b = 0; b < 2; b++) {
      int kk = k0 + b * 32;
      async16(gA0 + kk, As[b] + (wave * 2 + 0) * 512);
      async16(gA1 + kk, As[b] + (wave * 2 + 1) * 512);
      async16(gBi + kk, Bi[b] + wave * 512);
      async16(gBg + kk, Bg[b] + wave * 512);
    }
    __syncthreads();

#pragma unroll
    for (int b = 0; b < 2; b++) {
      short8 a[4];
#pragma unroll
      for (int i = 0; i < 4; i++)
        a[i] = *(const short8*)&As[b][(wm + i * 16 + lane16) * 32 + quad * 8];
#pragma unroll
      for (int j = 0; j < 2; j++) {
        short8 bi = *(const short8*)&Bi[b][(wn + j * 16 + lane16) * 32 + quad * 8];
#pragma unroll
        for (int i = 0; i < 4; i++)
          acc_i[i][j] = __builtin_amdgcn_mfma_f32_16x16x32_bf16(a[i], bi, acc_i[i][j], 0, 0, 0);
        short8 bg = *(const short8*)&Bg[b][(wn + j * 16 + lane16) * 32 + quad * 8];
#pragma unroll
        for (int i = 0; i < 4; i++)
          acc_g[i][j] = __builtin_amdgcn_mfma_f32_16x16x32_bf16(a[i], bg, acc_g[i][j], 0, 0, 0);
      }
    }
  }

  unsigned short* He = H + (size_t)e * CAP * IDIM;
#pragma unroll
  for (int i = 0; i < 4; i++) {
#pragma unroll
    for (int r = 0; r < 4; r++) {
      int m = m0 + wm + i * 16 + quad * 4 + r;
#pragma unroll
      for (int j = 0; j < 2; j++) {
        int n = i0 + wn + j * 16 + lane16;
        float vi = acc_i[i][j][r];
        float vg = acc_g[i][j][r];
        float h = 0.5f * vi * (1.0f + erff(vi * 0.70710678118654752f)) * vg;
        He[(size_t)m * IDIM + n] = f2b(h);
      }
    }
  }
}

// ---------------- GEMM2: full-K 128x128, gated atomic accumulate into out ----------------
// (R9's 128x64 retile was +8 µs — reverted to the R8-measured 128x128 form.)
__global__ __launch_bounds__(256, 4) void gemm2_kernel(const unsigned short* __restrict__ H,
                                                       const unsigned short* __restrict__ w2t,
                                                       const int* __restrict__ cnt,
                                                       const int* __restrict__ rowtok,
                                                       const float* __restrict__ rowgate,
                                                       float* __restrict__ out) {
  int e  = blockIdx.z;
  int m0 = blockIdx.y * 128;
  int n0 = blockIdx.x * 128;
  int cnte = cnt[e];
  if (m0 >= cnte) return;

  __shared__ __align__(16) unsigned char smem[32768];
  unsigned short* As[2] = { (unsigned short*)smem,           (unsigned short*)(smem + 8192) };
  unsigned short* Bs[2] = { (unsigned short*)(smem + 16384), (unsigned short*)(smem + 24576) };

  int tid  = threadIdx.x;
  int lane = tid & 63;
  int wave = tid >> 6;

  int sr0 = wave * 32 + (lane >> 2);
  int sr1 = sr0 + 16;
  int sk  = (lane & 3) * 8;

  const unsigned short* He  = H + (size_t)e * CAP * IDIM;
  const unsigned short* w2e = w2t + (size_t)e * DIM * IDIM;
  const unsigned short* gA0 = He + (size_t)(m0 + sr0) * IDIM + sk;
  const unsigned short* gA1 = He + (size_t)(m0 + sr1) * IDIM + sk;
  const unsigned short* gB0 = w2e + (size_t)(n0 + sr0) * IDIM + sk;
  const unsigned short* gB1 = w2e + (size_t)(n0 + sr1) * IDIM + sk;

  int lane16 = lane & 15;
  int quad   = lane >> 4;
  int wm = (wave & 1) * 64;
  int wn = (wave >> 1) * 64;

  floatx4 acc[4][4];
#pragma unroll
  for (int i = 0; i < 4; i++)
#pragma unroll
    for (int j = 0; j < 4; j++) acc[i][j] = (floatx4){0.f, 0.f, 0.f, 0.f};

  for (int k0 = 0; k0 < IDIM; k0 += 64) {
    __syncthreads();
#pragma unroll
    for (int b = 0; b < 2; b++) {
      int kk = k0 + b * 32;
      async16(gA0 + kk, As[b] + (wave * 2 + 0) * 512);
      async16(gA1 + kk, As[b] + (wave * 2 + 1) * 512);
      async16(gB0 + kk, Bs[b] + (wave * 2 + 0) * 512);
      async16(gB1 + kk, Bs[b] + (wave * 2 + 1) * 512);
    }
    __syncthreads();

#pragma unroll
    for (int b = 0; b < 2; b++) {
      short8 a[4];
#pragma unroll
      for (int i = 0; i < 4; i++)
        a[i] = *(const short8*)&As[b][(wm + i * 16 + lane16) * 32 + quad * 8];
#pragma unroll
      for (int j = 0; j < 4; j++) {
        short8 bb = *(const short8*)&Bs[b][(wn + j * 16 + lane16) * 32 + quad * 8];
#pragma unroll
        for (int i = 0; i < 4; i++)
          acc[i][j] = __builtin_amdgcn_mfma_f32_16x16x32_bf16(a[i], bb, acc[i][j], 0, 0, 0);
      }
    }
  }

#pragma unroll
  for (int i = 0; i < 4; i++) {
#pragma unroll
    for (int r = 0; r < 4; r++) {
      int m = m0 + wm + i * 16 + quad * 4 + r;
      if (m < cnte) {
        int tok = rowtok[e * CAP + m];
        float g = rowgate[e * CAP + m];
        float* orow = out + (size_t)tok * DIM;
#pragma unroll
        for (int j = 0; j < 4; j++) {
          int n = n0 + wn + j * 16 + lane16;
          atomicAdd(&orow[n], g * acc[i][j][r]);
        }
      }
    }
  }
}

// ---------------- launch ----------------
extern "C" void kernel_launch(void* const* d_in, const int* in_sizes, int n_in,
                              void* d_out, int out_size, void* d_ws, size_t ws_size,
                              hipStream_t stream) {
  const float* x  = (const float*)d_in[0];
  const float* Wg = (const float*)d_in[1];
  const float* W1 = (const float*)d_in[2];
  const float* W2 = (const float*)d_in[3];
  float* out = (float*)d_out;

  char* ws = (char*)d_ws;
  size_t off = 0;
  auto alloc = [&](size_t bytes) -> void* {
    void* p = ws + off;
    off = (off + bytes + 255) & ~(size_t)255;
    return p;
  };
  int*   top_i   = (int*)alloc((size_t)N_TOK * 2 * sizeof(int));
  float* gates   = (float*)alloc((size_t)N_TOK * 2 * sizeof(float));
  int*   rowtok  = (int*)alloc((size_t)NEXP * CAP * sizeof(int));
  float* rowgate = (float*)alloc((size_t)NEXP * CAP * sizeof(float));
  int*   cnt     = (int*)alloc((size_t)NEXP * sizeof(int));
  unsigned short* xb  = (unsigned short*)alloc((size_t)N_TOK * DIM * 2);
  unsigned short* w1t = (unsigned short*)alloc((size_t)NEXP * TWOI * DIM * 2);
  unsigned short* w2t = (unsigned short*)alloc((size_t)NEXP * DIM * IDIM * 2);
  unsigned short* Hb  = (unsigned short*)alloc((size_t)NEXP * CAP * IDIM * 2);
  if (off > ws_size) return;

  hipLaunchKernelGGL(prologue_kernel, dim3(W1_TBLOCKS + ROUTER_BLOCKS), dim3(256), 0, stream,
                     W1, w1t, x, Wg, xb, top_i, gates, out);
  hipLaunchKernelGGL(scan_kernel, dim3(1), dim3(1024), 0, stream,
                     top_i, gates, rowtok, rowgate, cnt);
  hipLaunchKernelGGL(gemm1_kernel, dim3(G1X, G1Y, NEXP + G1_TRANS_Z), dim3(256), 0, stream,
                     xb, w1t, rowtok, cnt, Hb, W2, w2t);
  hipLaunchKernelGGL(gemm2_kernel, dim3(DIM / 128, CAP / 128, NEXP), dim3(256), 0, stream,
                     Hb, w2t, cnt, rowtok, rowgate, out);
}